// Round 15
// baseline (345.314 us; speedup 1.0000x reference)
//
#include <hip/hip_runtime.h>
#include <hip/hip_bf16.h>
#include <math.h>

#define B_ 256
#define T_ 256
#define I_ 2048
#define H_ 128

#define BM 64
#define NKS 64   // K-steps of 32

typedef __attribute__((ext_vector_type(8))) short bf16x8;
typedef __attribute__((ext_vector_type(4))) float f32x4;
typedef _Float16 half2v __attribute__((ext_vector_type(2)));

static __device__ inline short f2bf(float f) {
    __hip_bfloat16 h = __float2bfloat16(f);
    return *reinterpret_cast<short*>(&h);
}

static __device__ inline bf16x8 pack8(float4 a, float4 b) {
    bf16x8 r;
    r[0] = f2bf(a.x); r[1] = f2bf(a.y); r[2] = f2bf(a.z); r[3] = f2bf(a.w);
    r[4] = f2bf(b.x); r[5] = f2bf(b.y); r[6] = f2bf(b.z); r[7] = f2bf(b.w);
    return r;
}

// barrier that drains ONLY lgkm (DS) — leaves global prefetch in flight
#define LGKM_BARRIER() do {                                  \
    asm volatile("s_waitcnt lgkmcnt(0)" ::: "memory");       \
    __builtin_amdgcn_sched_barrier(0);                       \
    __builtin_amdgcn_s_barrier();                            \
} while (0)

// ---------------------------------------------------------------------------
// Pre-kernel: W_ih fp32 -> bf16 (L2-resident B operand).
// ---------------------------------------------------------------------------
__global__ __launch_bounds__(256) void convW(
    const float* __restrict__ W, short* __restrict__ Wb)
{
    const int g = blockIdx.x * 256 + threadIdx.x;
    const float4 v0 = reinterpret_cast<const float4*>(W)[2 * g];
    const float4 v1 = reinterpret_cast<const float4*>(W)[2 * g + 1];
    reinterpret_cast<bf16x8*>(Wb)[g] = pack8(v0, v1);
}

// ---------------------------------------------------------------------------
// Kernel 1 v5: ZERO-LDS, ZERO-BARRIER projection.
// Every staged variant (R5/v2/v3/v4) clustered at 157-163 us with nothing
// saturated -> the block-wide stage->barrier->compute coupling was the
// limiter. Here each wave is fully independent: A-frags load straight
// global->VGPR (32 B contiguous per lane; 128 B contiguous per 4-lane
// row-group — same DRAM granularity as gl_lds staging), double-banked one
// K-step ahead; B-frags straight from L2-resident bf16 Wb. Latency hidden
// by TLP (4 waves/SIMD) + in-flight load depth (~50+ KB/CU).
// Block = 64 rows x 128 cols; wave (mh = wid&1, nh = wid>>1) owns
// rows [32*mh, +32) x cols [64*nh, +64): m=2, n=4 tiles of 16.
// ---------------------------------------------------------------------------
__global__ __launch_bounds__(256, 4) void proj_mfma(
    const float* __restrict__ x, const short* __restrict__ Wb,
    const float* __restrict__ bih, const float* __restrict__ bhh,
    float* __restrict__ xp)
{
    const int tid  = threadIdx.x;
    const int lane = tid & 63;
    const int wid  = tid >> 6;
    const int mh   = wid & 1;
    const int nh   = wid >> 1;
    const long row0 = (long)blockIdx.x * BM + mh * 32;
    const int  col0 = nh * 64;

    const int fr = lane & 15;
    const int fq = lane >> 4;

    // per-lane base pointers
    const float* ax0 = x + (row0 + fr) * I_ + fq * 8;        // m-tile 0
    const float* ax1 = x + (row0 + 16 + fr) * I_ + fq * 8;   // m-tile 1
    const short* bw  = Wb + (long)(col0 + fr) * I_ + fq * 8; // n-tile 0 row

    float biasr[4];
    #pragma unroll
    for (int n = 0; n < 4; ++n) {
        const int col = col0 + n * 16 + fr;
        biasr[n] = bih[col] + bhh[col];
    }

    f32x4 acc[2][4];
    #pragma unroll
    for (int m = 0; m < 2; ++m)
        #pragma unroll
        for (int n = 0; n < 4; ++n)
            acc[m][n] = (f32x4){0.f, 0.f, 0.f, 0.f};

    float4 Aa[4], Ab[4];   // banks: {m0.lo, m0.hi, m1.lo, m1.hi}

    auto LOADA = [&](int k, float4* bank) {
        bank[0] = *reinterpret_cast<const float4*>(ax0 + k);
        bank[1] = *reinterpret_cast<const float4*>(ax0 + k + 4);
        bank[2] = *reinterpret_cast<const float4*>(ax1 + k);
        bank[3] = *reinterpret_cast<const float4*>(ax1 + k + 4);
    };

    auto COMPUTE = [&](int t, float4* bank) {
        const bf16x8 a0 = pack8(bank[0], bank[1]);
        const bf16x8 a1 = pack8(bank[2], bank[3]);
        const short* bk = bw + t * 32;
        #pragma unroll
        for (int n = 0; n < 4; ++n) {
            const bf16x8 bf = *reinterpret_cast<const bf16x8*>(bk + (long)n * 16 * I_);
            acc[0][n] = __builtin_amdgcn_mfma_f32_16x16x32_bf16(a0, bf, acc[0][n], 0, 0, 0);
            acc[1][n] = __builtin_amdgcn_mfma_f32_16x16x32_bf16(a1, bf, acc[1][n], 0, 0, 0);
        }
    };

    LOADA(0, Aa);
    for (int t = 0; t < NKS; t += 2) {
        if (t + 1 < NKS) LOADA((t + 1) * 32, Ab);
        COMPUTE(t, Aa);
        if (t + 2 < NKS) LOADA((t + 2) * 32, Aa);
        COMPUTE(t + 1, Ab);
    }

    // epilogue: bias + store (C layout: row=(lane>>4)*4+i, col=lane&15)
    #pragma unroll
    for (int n = 0; n < 4; ++n) {
        const int col = col0 + n * 16 + fr;
        #pragma unroll
        for (int m = 0; m < 2; ++m) {
            const long rbase = row0 + m * 16 + fq * 4;
            #pragma unroll
            for (int i = 0; i < 4; ++i)
                xp[(rbase + i) * H_ + col] = acc[m][n][i] + biasr[n];
        }
    }
}

// ---------------------------------------------------------------------------
// Kernel 2 (FROZEN R9, measured ~65 us/pass): 4-wave scan, f16 packed h in
// LDS, v_dot2_f32_f16, shfl_xor(32) k-half combine, lgkm-only barrier,
// 4-deep xp prefetch.
// ---------------------------------------------------------------------------
__global__ __launch_bounds__(256) void scan_kernel(
    const float* __restrict__ xp, const float* __restrict__ Whh,
    const float* __restrict__ Wfc, const float* __restrict__ bfc,
    float* __restrict__ out)
{
    __shared__ __align__(16) unsigned hpk[2][H_ / 2];   // 64 u32 = 128 f16, dbuf

    const int tid  = threadIdx.x;
    const int lane = tid & 63;
    const int w    = tid >> 6;
    const int j    = w * 32 + (lane & 31);
    const int g    = lane >> 5;
    const int b    = blockIdx.x;

    half2v Wh[32];
    {
        const float4* wp = reinterpret_cast<const float4*>(&Whh[(long)j * H_ + g * 64]);
        #pragma unroll
        for (int q = 0; q < 16; ++q) {
            const float4 wv = wp[q];
            half2v p0, p1;
            p0[0] = (_Float16)wv.x; p0[1] = (_Float16)wv.y;
            p1[0] = (_Float16)wv.z; p1[1] = (_Float16)wv.w;
            Wh[2 * q]     = p0;
            Wh[2 * q + 1] = p1;
        }
    }
    if (tid < H_ / 2) hpk[0][tid] = 0u;

    const float* xprow = xp + (long)b * T_ * H_ + j;
    float xa = xprow[0 * H_];
    float xb = xprow[1 * H_];
    float xc = xprow[2 * H_];
    float xd = xprow[3 * H_];
    __syncthreads();

    auto body = [&](int t, float xpv) {
        const uint4* hp = reinterpret_cast<const uint4*>(&hpk[t & 1][g * 32]);
        float a0 = 0.f, a1 = 0.f, a2 = 0.f, a3 = 0.f;
        #pragma unroll
        for (int q = 0; q < 8; ++q) {
            const uint4 u = hp[q];
            a0 = __builtin_amdgcn_fdot2(__builtin_bit_cast(half2v, u.x), Wh[4*q+0], a0, false);
            a1 = __builtin_amdgcn_fdot2(__builtin_bit_cast(half2v, u.y), Wh[4*q+1], a1, false);
            a2 = __builtin_amdgcn_fdot2(__builtin_bit_cast(half2v, u.z), Wh[4*q+2], a2, false);
            a3 = __builtin_amdgcn_fdot2(__builtin_bit_cast(half2v, u.w), Wh[4*q+3], a3, false);
        }
        float part = (a0 + a1) + (a2 + a3);
        part += __shfl_xor(part, 32);
        const float pre = part + xpv;
        const float e = __expf(2.f * pre);      // tanh = 1 - 2/(e^{2x}+1)
        const float h = 1.f - 2.f / (e + 1.f);
        if (g == 0) {
            reinterpret_cast<unsigned short*>(&hpk[(t + 1) & 1][0])[j] =
                __builtin_bit_cast(unsigned short, (_Float16)h);
        }
        LGKM_BARRIER();
    };

    for (int t = 0; t < T_; t += 4) {
        float xu;
        xu = xa; if (t + 4 < T_) xa = xprow[(long)(t + 4) * H_];
        body(t + 0, xu);
        xu = xb; if (t + 5 < T_) xb = xprow[(long)(t + 5) * H_];
        body(t + 1, xu);
        xu = xc; if (t + 6 < T_) xc = xprow[(long)(t + 6) * H_];
        body(t + 2, xu);
        xu = xd; if (t + 7 < T_) xd = xprow[(long)(t + 7) * H_];
        body(t + 3, xu);
    }

    // final FC: h_T is in hpk[0] (t=255 wrote (255+1)&1 = 0)
    if (w == 0) {
        const unsigned u = hpk[0][lane];        // pair h[2l], h[2l+1]
        const half2v hh = __builtin_bit_cast(half2v, u);
        float v = (float)hh[0] * Wfc[2 * lane] + (float)hh[1] * Wfc[2 * lane + 1];
        #pragma unroll
        for (int off = 32; off > 0; off >>= 1) v += __shfl_down(v, off);
        if (lane == 0) out[b] = v + bfc[0];
    }
}

// ---------------------------------------------------------------------------
extern "C" void kernel_launch(void* const* d_in, const int* in_sizes, int n_in,
                              void* d_out, int out_size, void* d_ws, size_t ws_size,
                              hipStream_t stream)
{
    const float* x   = (const float*)d_in[0];
    const float* Wih = (const float*)d_in[1];
    const float* Whh = (const float*)d_in[2];
    const float* bih = (const float*)d_in[3];
    const float* bhh = (const float*)d_in[4];
    const float* Wfc = (const float*)d_in[5];
    const float* bfc = (const float*)d_in[6];
    float* out = (float*)d_out;
    float* xp  = (float*)d_ws;                       // 32 MB scratch
    short* Wb  = (short*)((char*)d_ws + (size_t)B_ * T_ * H_ * sizeof(float));  // bf16 W_ih

    convW<<<dim3((H_ * I_) / (256 * 8)), dim3(256), 0, stream>>>(Wih, Wb);
    proj_mfma<<<dim3((B_ * T_) / BM), dim3(256), 0, stream>>>(x, Wb, bih, bhh, xp);
    scan_kernel<<<dim3(B_), dim3(256), 0, stream>>>(xp, Whh, Wfc, bfc, out);
}

// Round 16
// 233.460 us; speedup vs baseline: 1.4791x; 1.4791x over previous
//
#include <hip/hip_runtime.h>
#include <hip/hip_bf16.h>
#include <math.h>

#define B_ 256
#define T_ 256
#define I_ 2048
#define H_ 128

#define BM 128
#define BK 32
#define NKT (I_ / BK)   // 64 K-tiles

typedef __attribute__((ext_vector_type(8))) short bf16x8;
typedef __attribute__((ext_vector_type(4))) float f32x4;
typedef _Float16 half2v __attribute__((ext_vector_type(2)));

static __device__ inline short f2bf(float f) {
    __hip_bfloat16 h = __float2bfloat16(f);
    return *reinterpret_cast<short*>(&h);
}

static __device__ inline bf16x8 pack8(float4 a, float4 b) {
    bf16x8 r;
    r[0] = f2bf(a.x); r[1] = f2bf(a.y); r[2] = f2bf(a.z); r[3] = f2bf(a.w);
    r[4] = f2bf(b.x); r[5] = f2bf(b.y); r[6] = f2bf(b.z); r[7] = f2bf(b.w);
    return r;
}

// barrier that drains ONLY lgkm (DS) — leaves global prefetch in flight
#define LGKM_BARRIER() do {                                  \
    asm volatile("s_waitcnt lgkmcnt(0)" ::: "memory");       \
    __builtin_amdgcn_sched_barrier(0);                       \
    __builtin_amdgcn_s_barrier();                            \
} while (0)

// B-row swizzle for 64-B bf16 rows (4 x 16B units): 2-way max = free
static __device__ inline int swzB(int r) { return (r & 3) ^ ((r >> 2) & 3); }

// ---------------------------------------------------------------------------
// Pre-kernel: W_ih fp32 -> bf16 (L2-resident B operand).
// ---------------------------------------------------------------------------
__global__ __launch_bounds__(256) void convW(
    const float* __restrict__ W, short* __restrict__ Wb)
{
    const int g = blockIdx.x * 256 + threadIdx.x;
    const float4 v0 = reinterpret_cast<const float4*>(W)[2 * g];
    const float4 v1 = reinterpret_cast<const float4*>(W)[2 * g + 1];
    reinterpret_cast<bf16x8*>(Wb)[g] = pack8(v0, v1);
}

// ---------------------------------------------------------------------------
// Kernel 1 (R5 structure + bf16 B): tile 128x128, BK=32, 4 waves (2x2),
// dbuf LDS, ONE __syncthreads per K-step, gl_lds staging.
//   A: fp32, 8 gl_lds/block, XOR-swz unit^(row&7) both-sides (proven R5).
//   B: bf16 (convW), 8 gl_lds/block (1 KB each), swz unit^swzB(row)
//      both-sides; frags read directly as bf16x8 (no pack VALU).
// LDS = 2x16(A) + 2x8(B) = 48 KB -> 3 blocks/CU (was 2): +50% phase-offset
// TLP to cover the per-barrier vmcnt drain (the measured 3.3 TB/s cap).
// ---------------------------------------------------------------------------
__global__ __launch_bounds__(256, 3) void proj_mfma(
    const float* __restrict__ x, const short* __restrict__ Wb,
    const float* __restrict__ bih, const float* __restrict__ bhh,
    float* __restrict__ xp)
{
    __shared__ __align__(16) float As[2][BM * BK];   // 2 x 16 KB
    __shared__ __align__(16) short Bs[2][H_ * BK];   // 2 x 8 KB

    const int tid  = threadIdx.x;
    const int lane = tid & 63;
    const int wid  = tid >> 6;
    const int wr   = wid >> 1;
    const int wc   = wid & 1;
    const long row0 = (long)blockIdx.x * BM;

    // A staging decode: 2 instr/wave, 8 rows x 128 B each
    const int srowA  = lane >> 3;                 // 0..7
    const int sunitA = (lane & 7) ^ srowA;        // swizzled 16B unit
    // B staging decode: 2 instr/wave, 16 rows x 64 B each
    const int srowB  = lane >> 2;                 // 0..15
    const int rb0 = wid * 32;                     // A row base per wave

    auto STAGE = [&](int tt, int buf) {
        const int kk = tt * BK;
        #pragma unroll
        for (int i = 0; i < 2; ++i) {
            const int rbase = rb0 + i * 16 + (srowA & 8);   // no-op split, keeps 8-row chunks
            const int r = rb0 + i * 16 + (lane >> 3) + ((i == i) ? 0 : 0);
            (void)rbase; (void)r;
        }
        // A: 2 chunks of 8 rows per wave
        #pragma unroll
        for (int i = 0; i < 2; ++i) {
            const int rA = rb0 + i * 8 + srowA;
            const float* ga = x + (row0 + rA) * I_ + kk + sunitA * 4;
            __builtin_amdgcn_global_load_lds(
                (const __attribute__((address_space(1))) void*)ga,
                (__attribute__((address_space(3))) void*)&As[buf][(rb0 + i * 8) * BK],
                16, 0, 0);
        }
        // A: remaining 2 chunks (rows rb0+16..rb0+31)
        #pragma unroll
        for (int i = 2; i < 4; ++i) {
            const int rA = rb0 + i * 8 + srowA;
            const float* ga = x + (row0 + rA) * I_ + kk + sunitA * 4;
            __builtin_amdgcn_global_load_lds(
                (const __attribute__((address_space(1))) void*)ga,
                (__attribute__((address_space(3))) void*)&As[buf][(rb0 + i * 8) * BK],
                16, 0, 0);
        }
        // B: 2 chunks of 16 rows per wave
        #pragma unroll
        for (int i = 0; i < 2; ++i) {
            const int rB = rb0 + i * 16 + srowB;
            const int u  = (lane & 3) ^ swzB(rB);
            const short* gb = Wb + (long)rB * I_ + kk + u * 8;
            __builtin_amdgcn_global_load_lds(
                (const __attribute__((address_space(1))) void*)gb,
                (__attribute__((address_space(3))) void*)&Bs[buf][(rb0 + i * 16) * BK],
                16, 0, 0);
        }
    };

    const int fr = lane & 15;
    const int fq = lane >> 4;

    f32x4 acc[4][4];
    #pragma unroll
    for (int m = 0; m < 4; ++m)
        #pragma unroll
        for (int n = 0; n < 4; ++n)
            acc[m][n] = (f32x4){0.f, 0.f, 0.f, 0.f};

    STAGE(0, 0);
    __syncthreads();

    int p = 0;
    for (int t = 0; t < NKT; ++t) {
        if (t + 1 < NKT) STAGE(t + 1, p ^ 1);   // in flight across this compute

        bf16x8 af[4], bfr[4];
        #pragma unroll
        for (int f = 0; f < 4; ++f) {
            const int ra_ = wr * 64 + f * 16 + fr;
            const float4 a0 = *reinterpret_cast<const float4*>(
                &As[p][ra_ * BK + (((fq * 2)     ^ (ra_ & 7)) * 4)]);
            const float4 a1 = *reinterpret_cast<const float4*>(
                &As[p][ra_ * BK + (((fq * 2 + 1) ^ (ra_ & 7)) * 4)]);
            af[f] = pack8(a0, a1);
            const int rb_ = wc * 64 + f * 16 + fr;
            bfr[f] = *reinterpret_cast<const bf16x8*>(
                &Bs[p][rb_ * BK + ((fq ^ swzB(rb_)) * 8)]);
        }
        #pragma unroll
        for (int m = 0; m < 4; ++m)
            #pragma unroll
            for (int n = 0; n < 4; ++n)
                acc[m][n] = __builtin_amdgcn_mfma_f32_16x16x32_bf16(
                    af[m], bfr[n], acc[m][n], 0, 0, 0);

        __syncthreads();   // buf p reads done; buf p^1 staging drained
        p ^= 1;
    }

    // epilogue: bias + store (C layout: row=(lane>>4)*4+j, col=lane&15)
    #pragma unroll
    for (int n = 0; n < 4; ++n) {
        const int col = wc * 64 + n * 16 + fr;
        const float bn = bih[col] + bhh[col];
        #pragma unroll
        for (int m = 0; m < 4; ++m) {
            const long rbase = row0 + wr * 64 + m * 16 + fq * 4;
            #pragma unroll
            for (int j = 0; j < 4; ++j)
                xp[(rbase + j) * H_ + col] = acc[m][n][j] + bn;
        }
    }
}

// ---------------------------------------------------------------------------
// Kernel 2 (FROZEN R9, measured ~65 us/pass): 4-wave scan, f16 packed h in
// LDS, v_dot2_f32_f16, shfl_xor(32) k-half combine, lgkm-only barrier,
// 4-deep xp prefetch.
// ---------------------------------------------------------------------------
__global__ __launch_bounds__(256) void scan_kernel(
    const float* __restrict__ xp, const float* __restrict__ Whh,
    const float* __restrict__ Wfc, const float* __restrict__ bfc,
    float* __restrict__ out)
{
    __shared__ __align__(16) unsigned hpk[2][H_ / 2];   // 64 u32 = 128 f16, dbuf

    const int tid  = threadIdx.x;
    const int lane = tid & 63;
    const int w    = tid >> 6;
    const int j    = w * 32 + (lane & 31);
    const int g    = lane >> 5;
    const int b    = blockIdx.x;

    half2v Wh[32];
    {
        const float4* wp = reinterpret_cast<const float4*>(&Whh[(long)j * H_ + g * 64]);
        #pragma unroll
        for (int q = 0; q < 16; ++q) {
            const float4 wv = wp[q];
            half2v p0, p1;
            p0[0] = (_Float16)wv.x; p0[1] = (_Float16)wv.y;
            p1[0] = (_Float16)wv.z; p1[1] = (_Float16)wv.w;
            Wh[2 * q]     = p0;
            Wh[2 * q + 1] = p1;
        }
    }
    if (tid < H_ / 2) hpk[0][tid] = 0u;

    const float* xprow = xp + (long)b * T_ * H_ + j;
    float xa = xprow[0 * H_];
    float xb = xprow[1 * H_];
    float xc = xprow[2 * H_];
    float xd = xprow[3 * H_];
    __syncthreads();

    auto body = [&](int t, float xpv) {
        const uint4* hp = reinterpret_cast<const uint4*>(&hpk[t & 1][g * 32]);
        float a0 = 0.f, a1 = 0.f, a2 = 0.f, a3 = 0.f;
        #pragma unroll
        for (int q = 0; q < 8; ++q) {
            const uint4 u = hp[q];
            a0 = __builtin_amdgcn_fdot2(__builtin_bit_cast(half2v, u.x), Wh[4*q+0], a0, false);
            a1 = __builtin_amdgcn_fdot2(__builtin_bit_cast(half2v, u.y), Wh[4*q+1], a1, false);
            a2 = __builtin_amdgcn_fdot2(__builtin_bit_cast(half2v, u.z), Wh[4*q+2], a2, false);
            a3 = __builtin_amdgcn_fdot2(__builtin_bit_cast(half2v, u.w), Wh[4*q+3], a3, false);
        }
        float part = (a0 + a1) + (a2 + a3);
        part += __shfl_xor(part, 32);
        const float pre = part + xpv;
        const float e = __expf(2.f * pre);      // tanh = 1 - 2/(e^{2x}+1)
        const float h = 1.f - 2.f / (e + 1.f);
        if (g == 0) {
            reinterpret_cast<unsigned short*>(&hpk[(t + 1) & 1][0])[j] =
                __builtin_bit_cast(unsigned short, (_Float16)h);
        }
        LGKM_BARRIER();
    };

    for (int t = 0; t < T_; t += 4) {
        float xu;
        xu = xa; if (t + 4 < T_) xa = xprow[(long)(t + 4) * H_];
        body(t + 0, xu);
        xu = xb; if (t + 5 < T_) xb = xprow[(long)(t + 5) * H_];
        body(t + 1, xu);
        xu = xc; if (t + 6 < T_) xc = xprow[(long)(t + 6) * H_];
        body(t + 2, xu);
        xu = xd; if (t + 7 < T_) xd = xprow[(long)(t + 7) * H_];
        body(t + 3, xu);
    }

    // final FC: h_T is in hpk[0] (t=255 wrote (255+1)&1 = 0)
    if (w == 0) {
        const unsigned u = hpk[0][lane];        // pair h[2l], h[2l+1]
        const half2v hh = __builtin_bit_cast(half2v, u);
        float v = (float)hh[0] * Wfc[2 * lane] + (float)hh[1] * Wfc[2 * lane + 1];
        #pragma unroll
        for (int off = 32; off > 0; off >>= 1) v += __shfl_down(v, off);
        if (lane == 0) out[b] = v + bfc[0];
    }
}

// ---------------------------------------------------------------------------
extern "C" void kernel_launch(void* const* d_in, const int* in_sizes, int n_in,
                              void* d_out, int out_size, void* d_ws, size_t ws_size,
                              hipStream_t stream)
{
    const float* x   = (const float*)d_in[0];
    const float* Wih = (const float*)d_in[1];
    const float* Whh = (const float*)d_in[2];
    const float* bih = (const float*)d_in[3];
    const float* bhh = (const float*)d_in[4];
    const float* Wfc = (const float*)d_in[5];
    const float* bfc = (const float*)d_in[6];
    float* out = (float*)d_out;
    float* xp  = (float*)d_ws;                       // 32 MB scratch
    short* Wb  = (short*)((char*)d_ws + (size_t)B_ * T_ * H_ * sizeof(float));  // bf16 W_ih

    convW<<<dim3((H_ * I_) / (256 * 8)), dim3(256), 0, stream>>>(Wih, Wb);
    proj_mfma<<<dim3((B_ * T_) / BM), dim3(256), 0, stream>>>(x, Wb, bih, bhh, xp);
    scan_kernel<<<dim3(B_), dim3(256), 0, stream>>>(xp, Whh, Wfc, bfc, out);
}